// Round 32
// baseline (85.805 us; speedup 1.0000x reference)
//
#include <hip/hip_runtime.h>

#define T_STEPS 2000
#define B_DIM 16
#define L_DIM 1024

// FitzHugh-Nagumo Euler — BIT-EXACT match to the XLA-compiled f32 jax ref
// (R30: absmax == 0.0). Pinned arithmetic schedule (flag-proof):
//   v3=(v*v)*v ; t2=c3*v3 ; a1=fma(1.1,v,-t2) ; a2=fma(-dt,s,a1)
//   vn=fma(dt,z,a2) ; u1=v+0.7 ; u3=fma(-0.8,s,u1) ; s'=fma(0.008,u3,s)
//   out=0.5*vn ; row 0 = 0
// R32: wave specialization to split vmcnt domains. R31's single wave issued
// 1 load + 1 nt-store per step into ONE in-order 6-bit vmcnt -> ring reuse
// needed vmcnt over 127 (inexpressible) -> forced waits on store acks.
// Now: w0 = compute + burst z-loads (double reg ring A/B; loads-only vmcnt,
// all complete before each barrier drain); w1 = all stores via 32KB LDS
// double buffer. Arithmetic untouched -> absmax must stay 0.
__device__ __forceinline__ float vmulf(float a, float b) {
    float d; asm("v_mul_f32 %0, %1, %2" : "=v"(d) : "v"(a), "v"(b)); return d;
}
__device__ __forceinline__ float vaddf(float a, float b) {
    float d; asm("v_add_f32 %0, %1, %2" : "=v"(d) : "v"(a), "v"(b)); return d;
}
__device__ __forceinline__ float vfma(float a, float b, float c) {
    float d; asm("v_fma_f32 %0, %1, %2, %3" : "=v"(d) : "v"(a), "v"(b), "v"(c)); return d;
}
__device__ __forceinline__ float vfma_negc(float a, float b, float c) {   // a*b - c
    float d; asm("v_fma_f32 %0, %1, %2, -%3" : "=v"(d) : "v"(a), "v"(b), "v"(c)); return d;
}
__device__ __forceinline__ float vfma_nega(float a, float b, float c) {   // -a*b + c
    float d; asm("v_fma_f32 %0, -%1, %2, %3" : "=v"(d) : "v"(a), "v"(b), "v"(c)); return d;
}

__global__ __launch_bounds__(128, 1) void fh_kernel(const float* __restrict__ z,
                                                    float* __restrict__ out) {
    const float C_1P = (float)(1.0 + 0.1);   // f32(1.1)
    const float C_3  = (float)(0.1 / 3.0);   // 0.033333335f
    const float C_DT = 0.1f;
    const float C_SK = (float)(0.1 * 0.08);  // 0.008f
    const float C_07 = 0.7f;
    const float C_08 = 0.8f;

    __shared__ float vbuf[2][64][64];        // [buf][step][lane], 32 KB

    const int wv = threadIdx.x >> 6;         // wave id: 0 compute, 1 store
    const int lane = threadIdx.x & 63;
    const int idx = blockIdx.x * 64 + lane;  // chain id 0..16383
    const int b = idx >> 10;
    const int l = idx & 1023;
    const size_t base = (size_t)b * T_STEPS * L_DIM + l;

    // 32 chunks: 0..30 full (64 steps), 31 = 15-step tail; 33 barrier phases.
    if (wv == 0) {
        const float* zp = z + base;
        float v = 0.0f, s = 0.0f;
        float ringA[64], ringB[64];

#pragma unroll
        for (int i = 0; i < 64; ++i)         // preload chunk 0
            ringA[i] = zp[(size_t)i * L_DIM];

#define FH_STEP(ZK, P, I)                                    \
        do {                                                 \
            const float v3 = vmulf(vmulf(v, v), v);          \
            const float t2 = vmulf(C_3, v3);                 \
            const float a1 = vfma_negc(C_1P, v, t2);         \
            const float a2 = vfma_nega(C_DT, s, a1);         \
            const float vn = vfma(C_DT, (ZK), a2);           \
            const float u1 = vaddf(v, C_07);                 \
            const float u3 = vfma_nega(C_08, s, u1);         \
            s = vfma(C_SK, u3, s);                           \
            v = vn;                                          \
            vbuf[P][I][lane] = vmulf(0.5f, v);               \
        } while (0)

        for (int pp = 0; pp < 15; ++pp) {    // phases 0..29 (chunks 0..29)
            {   // even phase 2pp: consume A, burst-prefetch into B
                const float* zpf = zp + (size_t)(2 * pp * 64 + 64) * L_DIM;
#pragma unroll
                for (int i = 0; i < 64; ++i) ringB[i] = zpf[(size_t)i * L_DIM];
#pragma unroll
                for (int i = 0; i < 64; ++i) { const float zk = ringA[i]; FH_STEP(zk, 0, i); }
                __syncthreads();
            }
            {   // odd phase 2pp+1: consume B, burst-prefetch into A
                const float* zpf = zp + (size_t)((2 * pp + 1) * 64 + 64) * L_DIM;
#pragma unroll
                for (int i = 0; i < 64; ++i) ringA[i] = zpf[(size_t)i * L_DIM];
#pragma unroll
                for (int i = 0; i < 64; ++i) { const float zk = ringB[i]; FH_STEP(zk, 1, i); }
                __syncthreads();
            }
        }
        {   // phase 30 (chunk 30): consume A, clamped tail prefetch into B
            const float* zpf = zp + (size_t)1984 * L_DIM;
#pragma unroll
            for (int i = 0; i < 64; ++i) {
                const int io = (i < 15) ? i : 14;     // z[1984..1998]
                ringB[i] = zpf[(size_t)io * L_DIM];
            }
#pragma unroll
            for (int i = 0; i < 64; ++i) { const float zk = ringA[i]; FH_STEP(zk, 0, i); }
            __syncthreads();
        }
        {   // phase 31 (chunk 31 tail): consume B[0..14]
#pragma unroll
            for (int i = 0; i < 15; ++i) { const float zk = ringB[i]; FH_STEP(zk, 1, i); }
            __syncthreads();
        }
        __syncthreads();                     // phase 32 (w1 stores chunk 31)
#undef FH_STEP
    } else {
        float* outp = out + base;
        __builtin_nontemporal_store(0.0f, outp);   // phase 0: k=0 row
        __syncthreads();
        for (int ph = 1; ph <= 32; ++ph) {   // store chunk ph-1
            const int c = ph - 1;
            const int len = (c == 31) ? 15 : 64;
            const int buf = c & 1;
            float* op = outp + (size_t)(c * 64 + 1) * L_DIM;
            for (int i = 0; i < len; ++i) {
                const float val = vbuf[buf][i][lane];
                __builtin_nontemporal_store(val, op);
                op += L_DIM;
            }
            __syncthreads();
        }
    }
}

extern "C" void kernel_launch(void* const* d_in, const int* in_sizes, int n_in,
                              void* d_out, int out_size, void* d_ws, size_t ws_size,
                              hipStream_t stream) {
    const float* z = (const float*)d_in[0];
    float* out = (float*)d_out;
    dim3 grid(256);                          // 256 blocks -> 1 block/CU
    dim3 block(128);                         // 2 waves: compute + store
    hipLaunchKernelGGL(fh_kernel, grid, block, 0, stream, z, out);
}